// Round 9
// baseline (349.720 us; speedup 1.0000x reference)
//
#include <hip/hip_runtime.h>
#include <stdint.h>

#define D_IN   2048
#define D_OUT  512

typedef __bf16 bf16;
typedef bf16     bf16x8 __attribute__((ext_vector_type(8)));
typedef float    f32x4  __attribute__((ext_vector_type(4)));
typedef uint32_t u32x4  __attribute__((ext_vector_type(4)));

#define GLP(p)  (const __attribute__((address_space(1))) void*)(p)
#define LDSP(p) (__attribute__((address_space(3))) void*)(p)

// ---------------- degree count ----------------
__global__ void k_count(const int* __restrict__ dstv, int* __restrict__ cnt, int E) {
    int e = blockIdx.x * blockDim.x + threadIdx.x;
    if (e < E) atomicAdd(&cnt[dstv[e]], 1);
}

// ---------------- hierarchical exclusive scan (+ dis, + cur=0) ----------------
__global__ __launch_bounds__(1024) void k_scan1(const int* __restrict__ cnt,
                                                int* __restrict__ offs,
                                                int* __restrict__ bsum,
                                                float* __restrict__ dis,
                                                int* __restrict__ cur, int n) {
    __shared__ int wsum[16], wbase[16];
    const int tid = threadIdx.x, lane = tid & 63, wv = tid >> 6;
    int i = blockIdx.x * 1024 + tid;
    int v = (i < n) ? cnt[i] : 0;
    int x = v;
    #pragma unroll
    for (int d = 1; d < 64; d <<= 1) {
        int y = __shfl_up(x, d);
        if (lane >= d) x += y;
    }
    if (lane == 63) wsum[wv] = x;
    __syncthreads();
    if (tid < 16) {
        int s = 0;
        for (int j = 0; j < tid; ++j) s += wsum[j];
        wbase[tid] = s;
    }
    __syncthreads();
    if (i < n) {
        offs[i] = wbase[wv] + x - v;            // block-local exclusive
        dis[i]  = rsqrtf((float)(v + 1));
        cur[i]  = 0;
    }
    if (tid == 0) bsum[blockIdx.x] = wbase[15] + wsum[15];
}

__global__ void k_scan2(int* __restrict__ bsum, int nb) {
    int t = threadIdx.x;
    if (nb <= 64) {
        int v = (t < nb) ? bsum[t] : 0;
        int x = v;
        #pragma unroll
        for (int d = 1; d < 64; d <<= 1) {
            int y = __shfl_up(x, d);
            if (t >= d) x += y;
        }
        if (t < nb) bsum[t] = x - v;   // exclusive
    } else if (t == 0) {
        int run = 0;
        for (int j = 0; j < nb; ++j) { int v = bsum[j]; bsum[j] = run; run += v; }
    }
}

// ---------------- CSR fill (offs = local + bsum); also nrm[p] = dis[src] ----------------
__global__ void k_fill(const int* __restrict__ srcv, const int* __restrict__ dstv,
                       const int* __restrict__ offs, const int* __restrict__ bsum,
                       const float* __restrict__ dis, int* __restrict__ cur,
                       int* __restrict__ csr, float* __restrict__ nrm, int E) {
    int e = blockIdx.x * blockDim.x + threadIdx.x;
    if (e < E) {
        int d = dstv[e];
        int s = srcv[e];
        int p = offs[d] + bsum[d >> 10] + atomicAdd(&cur[d], 1);
        csr[p] = s;
        nrm[p] = dis[s];
    }
}

// ---------------- weight transpose + bf16 cast: wt[n][k] = (bf16)W[k][n] ----------------
__global__ void k_wt(const float* __restrict__ W, uint16_t* __restrict__ wt) {
    __shared__ float t[32][33];
    int kb = blockIdx.x * 32, nb = blockIdx.y * 32;
    int tx = threadIdx.x, ty = threadIdx.y;
    #pragma unroll
    for (int i = 0; i < 32; i += 8)
        t[ty + i][tx] = W[(size_t)(kb + ty + i) * D_OUT + nb + tx];
    __syncthreads();
    bf16* o = (bf16*)wt;
    #pragma unroll
    for (int i = 0; i < 32; i += 8)
        o[(size_t)(nb + ty + i) * D_IN + kb + tx] = (bf16)t[tx][ty + i];
}

// ---------------- fused GEMM: H[M][512] = (bf16)X[M][2048](fp32) * W ----------------
// 128x128 tile, BK=64, 4 waves (2x2), 4x4 frags of 16x16x32.
// Pipeline (counted vmcnt, raw barriers, NO vmcnt(0) in loop):
//   A: global fp32 -> regs (issued 1 step ahead) -> cvt bf16 -> ds_write to
//      SINGLE-buffered lsA (registers are the second buffer).
//   B: global_load_lds bf16, DOUBLE-buffered, staged TWO steps ahead.
// Iter t: loadA(t+1) | compute(t) | s_barrier | stageB(t+2) | vmcnt(4)
//         | writeA(t+1) | lgkmcnt(0) | s_barrier.
// Queue invariant entering iter t: [B(t+1)x4]; vmcnt(4) retires B(t+1)+A(t+1).
// LDS 48 KB -> 3 blocks/CU. XOR involution u^(row&7) both sides.
__global__ __launch_bounds__(256, 3) void k_gemm(const float* __restrict__ X,
                                                 const uint16_t* __restrict__ WT,
                                                 uint16_t* __restrict__ H, int M) {
    __shared__ uint16_t lsA[128 * 64];      // 16 KB single
    __shared__ uint16_t lsB[2][128 * 64];   // 32 KB dbuf
    // bijective chunked XCD swizzle: one m-panel's 4 n-blocks -> same XCD
    const int nwg = gridDim.x;
    const int b = blockIdx.x;
    const int q = nwg >> 3, r = nwg & 7;
    const int xcd = b & 7, lo = b >> 3;
    const int g = (xcd < r) ? (xcd * (q + 1) + lo) : (r * (q + 1) + (xcd - r) * q + lo);
    const int m0 = (g >> 2) * 128;
    const int n0 = (g & 3) * 128;
    const int tid = threadIdx.x;
    const int w = tid >> 6, lane = tid & 63;
    const int wr = w >> 1, wc = w & 1;
    const int lr = lane & 15, lk = lane >> 4;
    const int NT = D_IN / 64;   // 32

    f32x4 acc[4][4];
    #pragma unroll
    for (int m = 0; m < 4; m++)
        #pragma unroll
        for (int n = 0; n < 4; n++) acc[m][n] = (f32x4)(0.0f);

    // staging coords: unit uidx=(w*4+j)*64+lane; row=uidx>>3, u=uidx&7
    const float* aSrc[4];
    int aDst[4];
    const uint16_t* bSrc[4];
    #pragma unroll
    for (int j = 0; j < 4; j++) {
        int uidx = (w * 4 + j) * 64 + lane;
        int row = uidx >> 3, u = uidx & 7;
        int lrow = row;
        if (m0 + row >= M) lrow = (M - 1) - m0;   // clamp: valid data staged, stores masked
        aSrc[j] = X + (size_t)(m0 + lrow) * D_IN + u * 8;               // linear global (fp32)
        aDst[j] = row * 64 + (u ^ (row & 7)) * 8;                       // swizzled LDS (bf16 elems)
        bSrc[j] = WT + (size_t)(n0 + row) * D_IN + (u ^ (row & 7)) * 8; // pre-swizzled global
    }

    f32x4 ar[8];   // A prefetch registers (8 floats/unit x 4 units)

    auto loadA = [&](int t) {
        t &= (NT - 1);                           // wrap: tail stages dummies
        #pragma unroll
        for (int j = 0; j < 4; j++) {
            ar[2 * j]     = *(const f32x4*)(aSrc[j] + t * 64);
            ar[2 * j + 1] = *(const f32x4*)(aSrc[j] + t * 64 + 4);
        }
    };
    auto writeA = [&]() {
        #pragma unroll
        for (int j = 0; j < 4; j++) {
            f32x4 a0 = ar[2 * j], a1 = ar[2 * j + 1];
            bf16x8 tv;
            tv[0] = (bf16)a0[0]; tv[1] = (bf16)a0[1]; tv[2] = (bf16)a0[2]; tv[3] = (bf16)a0[3];
            tv[4] = (bf16)a1[0]; tv[5] = (bf16)a1[1]; tv[6] = (bf16)a1[2]; tv[7] = (bf16)a1[3];
            *(bf16x8*)(&lsA[aDst[j]]) = tv;
        }
    };
    auto stageB = [&](int t, int buf) {
        t &= (NT - 1);
        #pragma unroll
        for (int j = 0; j < 4; j++)
            __builtin_amdgcn_global_load_lds(GLP(bSrc[j] + t * 64),
                                             LDSP(&lsB[buf][(w * 4 + j) * 512]), 16, 0, 0);
    };
    auto compute = [&](int buf) {
        #pragma unroll
        for (int kk = 0; kk < 2; kk++) {
            bf16x8 aF[4], bF[4];
            #pragma unroll
            for (int m = 0; m < 4; m++) {
                int row = wr * 64 + m * 16 + lr;
                aF[m] = *(const bf16x8*)(&lsA[row * 64 + (((kk * 4 + lk) ^ (row & 7)) * 8)]);
            }
            #pragma unroll
            for (int n = 0; n < 4; n++) {
                int row = wc * 64 + n * 16 + lr;
                bF[n] = *(const bf16x8*)(&lsB[buf][row * 64 + (((kk * 4 + lk) ^ (row & 7)) * 8)]);
            }
            #pragma unroll
            for (int m = 0; m < 4; m++)
                #pragma unroll
                for (int n = 0; n < 4; n++)
                    acc[m][n] = __builtin_amdgcn_mfma_f32_16x16x32_bf16(aF[m], bF[n], acc[m][n], 0, 0, 0);
        }
    };

    // prologue: lsA=tile0, lsB[0]=B(0) confirmed, queue=[B(1)x4]
    loadA(0);                                              // [A0_8]
    stageB(0, 0);                                          // [A0,B0]=12
    stageB(1, 1);                                          // [A0,B0,B1]=16
    asm volatile("s_waitcnt vmcnt(8)" ::: "memory");       // A0 retired
    writeA();                                              // lsA = tile 0
    asm volatile("s_waitcnt vmcnt(4)" ::: "memory");       // B0 retired, B1 in flight
    asm volatile("s_waitcnt lgkmcnt(0)" ::: "memory");
    __builtin_amdgcn_s_barrier();

    #pragma unroll 1
    for (int t = 0; t < NT; t += 2) {
        // even iter: compute lsB[0]
        loadA(t + 1);                                      // [B(t+1), A(t+1)] = 12
        compute(0);
        __builtin_amdgcn_s_barrier();                      // all reads of lsA/lsB[0] done
        stageB(t + 2, 0);                                  // = 16
        asm volatile("s_waitcnt vmcnt(4)" ::: "memory");   // B(t+1)+A(t+1) retired
        writeA();                                          // lsA = tile t+1
        asm volatile("s_waitcnt lgkmcnt(0)" ::: "memory");
        __builtin_amdgcn_s_barrier();                      // tile t+1 published
        // odd iter: compute lsB[1]
        loadA(t + 2);
        compute(1);
        __builtin_amdgcn_s_barrier();
        stageB(t + 3, 1);
        asm volatile("s_waitcnt vmcnt(4)" ::: "memory");
        writeA();
        asm volatile("s_waitcnt lgkmcnt(0)" ::: "memory");
        __builtin_amdgcn_s_barrier();
    }
    asm volatile("s_waitcnt vmcnt(0)" ::: "memory");       // drain dummy DMAs before exit

    // epilogue: C/D layout col=lane&15, row=(lane>>4)*4+reg; store bf16
    #pragma unroll
    for (int m = 0; m < 4; m++) {
        int rbase = m0 + wr * 64 + m * 16 + lk * 4;
        #pragma unroll
        for (int n = 0; n < 4; n++) {
            int col = n0 + wc * 64 + n * 16 + lr;
            #pragma unroll
            for (int j = 0; j < 4; j++) {
                int row = rbase + j;
                if (row < M) {
                    bf16 tv = (bf16)acc[m][n][j];
                    H[(size_t)row * D_OUT + col] = __builtin_bit_cast(uint16_t, tv);
                }
            }
        }
    }
}

// ---------------- aggregation + bias + log_softmax, one wave per node ----------------
// edge loop unrolled x4; nrm[] read linearly (no random dis gather)
__global__ __launch_bounds__(256) void k_agg(const uint16_t* __restrict__ h,
                                             const int* __restrict__ csr,
                                             const float* __restrict__ nrm,
                                             const int* __restrict__ offs,
                                             const int* __restrict__ bsum,
                                             const int* __restrict__ cnt,
                                             const float* __restrict__ dis,
                                             const float* __restrict__ bias,
                                             float* __restrict__ out, int N) {
    const int wv = threadIdx.x >> 6, lane = threadIdx.x & 63;
    const int i = blockIdx.x * 4 + wv;
    if (i >= N) return;
    const float di = dis[i];
    float acc[8];
    {
        u32x4 v = *(const u32x4*)(h + (size_t)i * D_OUT + lane * 8);
        float s2 = di * di;
        #pragma unroll
        for (int k = 0; k < 4; k++) {
            acc[2 * k]     = __builtin_bit_cast(float, v[k] << 16) * s2;
            acc[2 * k + 1] = __builtin_bit_cast(float, v[k] & 0xffff0000u) * s2;
        }
    }
    const int o = offs[i] + bsum[i >> 10], cend = o + cnt[i];
    int e = o;
    for (; e + 4 <= cend; e += 4) {
        int s0 = csr[e], s1 = csr[e + 1], s2 = csr[e + 2], s3 = csr[e + 3];
        float w0 = di * nrm[e],     w1 = di * nrm[e + 1];
        float w2 = di * nrm[e + 2], w3 = di * nrm[e + 3];
        u32x4 v0 = *(const u32x4*)(h + (size_t)s0 * D_OUT + lane * 8);
        u32x4 v1 = *(const u32x4*)(h + (size_t)s1 * D_OUT + lane * 8);
        u32x4 v2 = *(const u32x4*)(h + (size_t)s2 * D_OUT + lane * 8);
        u32x4 v3 = *(const u32x4*)(h + (size_t)s3 * D_OUT + lane * 8);
        #pragma unroll
        for (int k = 0; k < 4; k++) {
            acc[2 * k]     += __builtin_bit_cast(float, v0[k] << 16) * w0
                            + __builtin_bit_cast(float, v1[k] << 16) * w1
                            + __builtin_bit_cast(float, v2[k] << 16) * w2
                            + __builtin_bit_cast(float, v3[k] << 16) * w3;
            acc[2 * k + 1] += __builtin_bit_cast(float, v0[k] & 0xffff0000u) * w0
                            + __builtin_bit_cast(float, v1[k] & 0xffff0000u) * w1
                            + __builtin_bit_cast(float, v2[k] & 0xffff0000u) * w2
                            + __builtin_bit_cast(float, v3[k] & 0xffff0000u) * w3;
        }
    }
    for (; e < cend; ++e) {
        int s0 = csr[e];
        float w0 = di * nrm[e];
        u32x4 v0 = *(const u32x4*)(h + (size_t)s0 * D_OUT + lane * 8);
        #pragma unroll
        for (int k = 0; k < 4; k++) {
            acc[2 * k]     += __builtin_bit_cast(float, v0[k] << 16) * w0;
            acc[2 * k + 1] += __builtin_bit_cast(float, v0[k] & 0xffff0000u) * w0;
        }
    }
    {
        const f32x4* bp = (const f32x4*)(bias + lane * 8);
        f32x4 b0 = bp[0], b1 = bp[1];
        #pragma unroll
        for (int k = 0; k < 4; k++) { acc[k] += b0[k]; acc[4 + k] += b1[k]; }
    }
    float mx = acc[0];
    #pragma unroll
    for (int k = 1; k < 8; k++) mx = fmaxf(mx, acc[k]);
    #pragma unroll
    for (int d = 1; d < 64; d <<= 1) mx = fmaxf(mx, __shfl_xor(mx, d));
    float se = 0.f;
    #pragma unroll
    for (int k = 0; k < 8; k++) se += expf(acc[k] - mx);
    #pragma unroll
    for (int d = 1; d < 64; d <<= 1) se += __shfl_xor(se, d);
    float lse = mx + logf(se);
    f32x4 o0, o1;
    #pragma unroll
    for (int k = 0; k < 4; k++) { o0[k] = acc[k] - lse; o1[k] = acc[4 + k] - lse; }
    f32x4* op = (f32x4*)(out + (size_t)i * D_OUT + lane * 8);
    op[0] = o0; op[1] = o1;
}

// ---------------- launch ----------------
extern "C" void kernel_launch(void* const* d_in, const int* in_sizes, int n_in,
                              void* d_out, int out_size, void* d_ws, size_t ws_size,
                              hipStream_t stream) {
    const float* x    = (const float*)d_in[0];
    const int*   ei   = (const int*)d_in[1];
    const float* W    = (const float*)d_in[2];
    const float* bias = (const float*)d_in[3];
    float* out = (float*)d_out;

    const int N = in_sizes[0] / D_IN;     // 50000
    const int E = in_sizes[1] / 2;        // 400000
    const int* srcv = ei;
    const int* dstv = ei + E;

    char* p = (char*)d_ws;
    auto carve = [&](size_t b) { void* r = (void*)p; p += (b + 255) & ~(size_t)255; return r; };
    uint16_t* h    = (uint16_t*)carve((size_t)N * D_OUT * 2);            // 51.2 MB
    uint16_t* wt   = (uint16_t*)carve((size_t)D_OUT * D_IN * 2);         // 2 MB
    int*      cnt  = (int*)carve((size_t)N * 4);
    int*      cur  = (int*)carve((size_t)N * 4);
    float*    dis  = (float*)carve((size_t)N * 4);
    int*      offs = (int*)carve((size_t)N * 4);
    int*      csr  = (int*)carve((size_t)E * 4);
    float*    nrm  = (float*)carve((size_t)E * 4);
    int*      bsum = (int*)carve(1024 * 4);

    hipMemsetAsync(cnt, 0, (size_t)N * 4, stream);

    k_wt<<<dim3(D_IN / 32, D_OUT / 32), dim3(32, 8), 0, stream>>>(W, wt);
    k_count<<<(E + 255) / 256, 256, 0, stream>>>(dstv, cnt, E);
    const int nb = (N + 1023) / 1024;
    k_scan1<<<nb, 1024, 0, stream>>>(cnt, offs, bsum, dis, cur, N);
    k_scan2<<<1, 64, 0, stream>>>(bsum, nb);
    k_fill<<<(E + 255) / 256, 256, 0, stream>>>(srcv, dstv, offs, bsum, dis, cur, csr, nrm, E);

    k_gemm<<<((N + 127) / 128) * 4, 256, 0, stream>>>(x, wt, h, N);

    k_agg<<<(N + 3) / 4, 256, 0, stream>>>(h, csr, nrm, offs, bsum, cnt, dis, bias, out, N);
}

// Round 10
// 344.713 us; speedup vs baseline: 1.0145x; 1.0145x over previous
//
#include <hip/hip_runtime.h>
#include <stdint.h>

#define D_IN   2048
#define D_OUT  512

typedef __bf16 bf16;
typedef bf16     bf16x8 __attribute__((ext_vector_type(8)));
typedef float    f32x4  __attribute__((ext_vector_type(4)));
typedef uint32_t u32x4  __attribute__((ext_vector_type(4)));

#define GLP(p)  (const __attribute__((address_space(1))) void*)(p)
#define LDSP(p) (__attribute__((address_space(3))) void*)(p)

// ---------------- degree count ----------------
__global__ void k_count(const int* __restrict__ dstv, int* __restrict__ cnt, int E) {
    int e = blockIdx.x * blockDim.x + threadIdx.x;
    if (e < E) atomicAdd(&cnt[dstv[e]], 1);
}

// ---------------- hierarchical exclusive scan (+ dis, + cur=0) ----------------
__global__ __launch_bounds__(1024) void k_scan1(const int* __restrict__ cnt,
                                                int* __restrict__ offs,
                                                int* __restrict__ bsum,
                                                float* __restrict__ dis,
                                                int* __restrict__ cur, int n) {
    __shared__ int wsum[16], wbase[16];
    const int tid = threadIdx.x, lane = tid & 63, wv = tid >> 6;
    int i = blockIdx.x * 1024 + tid;
    int v = (i < n) ? cnt[i] : 0;
    int x = v;
    #pragma unroll
    for (int d = 1; d < 64; d <<= 1) {
        int y = __shfl_up(x, d);
        if (lane >= d) x += y;
    }
    if (lane == 63) wsum[wv] = x;
    __syncthreads();
    if (tid < 16) {
        int s = 0;
        for (int j = 0; j < tid; ++j) s += wsum[j];
        wbase[tid] = s;
    }
    __syncthreads();
    if (i < n) {
        offs[i] = wbase[wv] + x - v;            // block-local exclusive
        dis[i]  = rsqrtf((float)(v + 1));
        cur[i]  = 0;
    }
    if (tid == 0) bsum[blockIdx.x] = wbase[15] + wsum[15];
}

__global__ void k_scan2(int* __restrict__ bsum, int nb) {
    int t = threadIdx.x;
    if (nb <= 64) {
        int v = (t < nb) ? bsum[t] : 0;
        int x = v;
        #pragma unroll
        for (int d = 1; d < 64; d <<= 1) {
            int y = __shfl_up(x, d);
            if (t >= d) x += y;
        }
        if (t < nb) bsum[t] = x - v;   // exclusive
    } else if (t == 0) {
        int run = 0;
        for (int j = 0; j < nb; ++j) { int v = bsum[j]; bsum[j] = run; run += v; }
    }
}

// ---------------- CSR fill (offs = local + bsum); also nrm[p] = dis[src] ----------------
__global__ void k_fill(const int* __restrict__ srcv, const int* __restrict__ dstv,
                       const int* __restrict__ offs, const int* __restrict__ bsum,
                       const float* __restrict__ dis, int* __restrict__ cur,
                       int* __restrict__ csr, float* __restrict__ nrm, int E) {
    int e = blockIdx.x * blockDim.x + threadIdx.x;
    if (e < E) {
        int d = dstv[e];
        int s = srcv[e];
        int p = offs[d] + bsum[d >> 10] + atomicAdd(&cur[d], 1);
        csr[p] = s;
        nrm[p] = dis[s];
    }
}

// ---------------- weight transpose + bf16 cast: wt[n][k] = (bf16)W[k][n] ----------------
__global__ void k_wt(const float* __restrict__ W, uint16_t* __restrict__ wt) {
    __shared__ float t[32][33];
    int kb = blockIdx.x * 32, nb = blockIdx.y * 32;
    int tx = threadIdx.x, ty = threadIdx.y;
    #pragma unroll
    for (int i = 0; i < 32; i += 8)
        t[ty + i][tx] = W[(size_t)(kb + ty + i) * D_OUT + nb + tx];
    __syncthreads();
    bf16* o = (bf16*)wt;
    #pragma unroll
    for (int i = 0; i < 32; i += 8)
        o[(size_t)(nb + ty + i) * D_IN + kb + tx] = (bf16)t[tx][ty + i];
}

// ---------------- fused GEMM, 8-phase-style schedule ----------------
// H[M][512] = (bf16)X[M][2048](fp32) * W.  BM=128, BN=256, BK=64.
// 512 threads = 8 waves (2M x 4N); per-wave output 64x64 (4m x 4n frags).
// LDS (dynamic 128KB): 2 slots x {A fp32 128x64 (32KB), B bf16 256x64 (32KB)}.
// Tile t reads slot t&1; during tile t's 4 phases, stage tile t+1 into the
// other slot (1 half per phase: A-h0, A-h1, B-h0, B-h1; 2 gload_lds each).
// Phase m: {ds_read aF[m] (+ bF x8 at m==0, held in regs) | stage half |
//   barrier | setprio(1) 8 MFMA setprio(0) | (m==3: vmcnt(0)) | barrier}.
// Swizzles: A rows = 16 x 16B units, involution u^(row&15); B rows = 8 units,
// u^(row&7). Both applied to pre-swizzled global source + swizzled LDS read;
// gload_lds dest is linear (wave-uniform base + lane*16).
__global__ __launch_bounds__(512, 1) void k_gemm(const float* __restrict__ X,
                                                 const uint16_t* __restrict__ WT,
                                                 uint16_t* __restrict__ H, int M) {
    extern __shared__ char smem[];
    float*    lsA = (float*)smem;                  // 2 x 8192 floats
    uint16_t* lsB = (uint16_t*)(smem + 65536);     // 2 x 16384 bf16

    // bijective chunked XCD swizzle: one m-panel's 2 n-blocks -> same XCD
    const int nwg = gridDim.x;
    const int b = blockIdx.x;
    const int q = nwg >> 3, r = nwg & 7;
    const int xcd = b & 7, lo = b >> 3;
    const int g = (xcd < r) ? (xcd * (q + 1) + lo) : (r * (q + 1) + (xcd - r) * q + lo);
    const int m0 = (g >> 1) * 128;
    const int n0 = (g & 1) * 256;
    const int tid = threadIdx.x;
    const int w = tid >> 6, lane = tid & 63;
    const int wr = w >> 2, wc = w & 3;             // 2M x 4N wave grid
    const int lr = lane & 15, lk = lane >> 4;
    const int NT = D_IN / 64;                      // 32 K-tiles

    f32x4 acc[4][4];
    #pragma unroll
    for (int m = 0; m < 4; m++)
        #pragma unroll
        for (int n = 0; n < 4; n++) acc[m][n] = (f32x4)(0.0f);

    // --- staging coords (per thread: 4 A units, 4 B units per tile) ---
    // A: unit L = h*1024 + j*512 + tid  (h=half, j=0..1); row=L>>4, u=L&15
    const float* aS[4]; int aD[4];
    #pragma unroll
    for (int h = 0; h < 2; h++)
        #pragma unroll
        for (int j = 0; j < 2; j++) {
            int L = h * 1024 + j * 512 + tid;
            int row = L >> 4, u = L & 15;
            int lrow = row;
            if (m0 + row >= M) lrow = (M - 1) - m0;   // tail clamp (stores masked)
            aS[h * 2 + j] = X + (size_t)(m0 + lrow) * D_IN + (u ^ (row & 15)) * 4;
            aD[h * 2 + j] = L * 4;                    // float offset (linear dest)
        }
    // B: unit L = h*1024 + j*512 + tid; row=L>>3, u=L&7
    const uint16_t* bS[4]; int bD[4];
    #pragma unroll
    for (int h = 0; h < 2; h++)
        #pragma unroll
        for (int j = 0; j < 2; j++) {
            int L = h * 1024 + j * 512 + tid;
            int row = L >> 3, u = L & 7;
            bS[h * 2 + j] = WT + (size_t)(n0 + row) * D_IN + (u ^ (row & 7)) * 8;
            bD[h * 2 + j] = L * 8;                    // bf16 offset (linear dest)
        }

    auto stageHalf = [&](int tn, int sn, int half) {  // half 0,1=A; 2,3=B
        if (half < 2) {
            #pragma unroll
            for (int j = 0; j < 2; j++)
                __builtin_amdgcn_global_load_lds(GLP(aS[half * 2 + j] + tn * 64),
                    LDSP(lsA + sn * 8192 + aD[half * 2 + j]), 16, 0, 0);
        } else {
            #pragma unroll
            for (int j = 0; j < 2; j++)
                __builtin_amdgcn_global_load_lds(GLP(bS[(half - 2) * 2 + j] + tn * 64),
                    LDSP(lsB + sn * 16384 + bD[(half - 2) * 2 + j]), 16, 0, 0);
        }
    };

    auto TILE = [&](int t, int sc, bool stageNext) {
        const float*    A_c = lsA + sc * 8192;
        const uint16_t* B_c = lsB + sc * 16384;
        const int sn = sc ^ 1;
        bf16x8 bF[4][2];
        #pragma unroll
        for (int m = 0; m < 4; m++) {
            // ---- ds_reads for this phase (slot sc is stable all tile) ----
            if (m == 0) {
                #pragma unroll
                for (int n = 0; n < 4; n++) {
                    int row = wc * 64 + n * 16 + lr;
                    #pragma unroll
                    for (int kk = 0; kk < 2; kk++)
                        bF[n][kk] = *(const bf16x8*)(B_c + row * 64 +
                                     (((kk * 4 + lk) ^ (row & 7)) * 8));
                }
            }
            bf16x8 aF[2];
            {
                int row = wr * 64 + m * 16 + lr;
                const float* base = A_c + row * 64;
                #pragma unroll
                for (int kk = 0; kk < 2; kk++) {
                    int u0 = kk * 8 + lk * 2;
                    f32x4 a0 = *(const f32x4*)(base + ((u0    ) ^ (row & 15)) * 4);
                    f32x4 a1 = *(const f32x4*)(base + ((u0 + 1) ^ (row & 15)) * 4);
                    bf16x8 tv;
                    tv[0] = (bf16)a0[0]; tv[1] = (bf16)a0[1]; tv[2] = (bf16)a0[2]; tv[3] = (bf16)a0[3];
                    tv[4] = (bf16)a1[0]; tv[5] = (bf16)a1[1]; tv[6] = (bf16)a1[2]; tv[7] = (bf16)a1[3];
                    aF[kk] = tv;
                }
            }
            // ---- stage one half of tile t+1 into slot sn ----
            if (stageNext) stageHalf(t + 1, sn, m);
            asm volatile("" ::: "memory");
            __builtin_amdgcn_s_barrier();
            asm volatile("" ::: "memory");
            __builtin_amdgcn_s_setprio(1);
            #pragma unroll
            for (int n = 0; n < 4; n++)
                #pragma unroll
                for (int kk = 0; kk < 2; kk++)
                    acc[m][n] = __builtin_amdgcn_mfma_f32_16x16x32_bf16(aF[kk], bF[n][kk], acc[m][n], 0, 0, 0);
            __builtin_amdgcn_s_setprio(0);
            if (m == 3)
                asm volatile("s_waitcnt vmcnt(0)" ::: "memory");  // tile t+1 arrived
            asm volatile("" ::: "memory");
            __builtin_amdgcn_s_barrier();
        }
    };

    // prologue: stage tile 0 into slot 0, wait, publish
    #pragma unroll
    for (int hh = 0; hh < 4; hh++) stageHalf(0, 0, hh);
    asm volatile("s_waitcnt vmcnt(0)" ::: "memory");
    __builtin_amdgcn_s_barrier();
    asm volatile("" ::: "memory");

    #pragma unroll 1
    for (int t = 0; t < NT; t += 2) {
        TILE(t,     0, true);
        TILE(t + 1, 1, t + 2 < NT);
    }

    // epilogue: C/D layout col=lane&15, row=(lane>>4)*4+reg; store bf16
    #pragma unroll
    for (int m = 0; m < 4; m++) {
        int rbase = m0 + wr * 64 + m * 16 + lk * 4;
        #pragma unroll
        for (int n = 0; n < 4; n++) {
            int col = n0 + wc * 64 + n * 16 + lr;
            #pragma unroll
            for (int j = 0; j < 4; j++) {
                int row = rbase + j;
                if (row < M) {
                    bf16 tv = (bf16)acc[m][n][j];
                    H[(size_t)row * D_OUT + col] = __builtin_bit_cast(uint16_t, tv);
                }
            }
        }
    }
}

// ---------------- aggregation + bias + log_softmax, one wave per node ----------------
__global__ __launch_bounds__(256) void k_agg(const uint16_t* __restrict__ h,
                                             const int* __restrict__ csr,
                                             const float* __restrict__ nrm,
                                             const int* __restrict__ offs,
                                             const int* __restrict__ bsum,
                                             const int* __restrict__ cnt,
                                             const float* __restrict__ dis,
                                             const float* __restrict__ bias,
                                             float* __restrict__ out, int N) {
    const int wv = threadIdx.x >> 6, lane = threadIdx.x & 63;
    const int i = blockIdx.x * 4 + wv;
    if (i >= N) return;
    const float di = dis[i];
    float acc[8];
    {
        u32x4 v = *(const u32x4*)(h + (size_t)i * D_OUT + lane * 8);
        float s2 = di * di;
        #pragma unroll
        for (int k = 0; k < 4; k++) {
            acc[2 * k]     = __builtin_bit_cast(float, v[k] << 16) * s2;
            acc[2 * k + 1] = __builtin_bit_cast(float, v[k] & 0xffff0000u) * s2;
        }
    }
    const int o = offs[i] + bsum[i >> 10], cend = o + cnt[i];
    int e = o;
    for (; e + 4 <= cend; e += 4) {
        int s0 = csr[e], s1 = csr[e + 1], s2 = csr[e + 2], s3 = csr[e + 3];
        float w0 = di * nrm[e],     w1 = di * nrm[e + 1];
        float w2 = di * nrm[e + 2], w3 = di * nrm[e + 3];
        u32x4 v0 = *(const u32x4*)(h + (size_t)s0 * D_OUT + lane * 8);
        u32x4 v1 = *(const u32x4*)(h + (size_t)s1 * D_OUT + lane * 8);
        u32x4 v2 = *(const u32x4*)(h + (size_t)s2 * D_OUT + lane * 8);
        u32x4 v3 = *(const u32x4*)(h + (size_t)s3 * D_OUT + lane * 8);
        #pragma unroll
        for (int k = 0; k < 4; k++) {
            acc[2 * k]     += __builtin_bit_cast(float, v0[k] << 16) * w0
                            + __builtin_bit_cast(float, v1[k] << 16) * w1
                            + __builtin_bit_cast(float, v2[k] << 16) * w2
                            + __builtin_bit_cast(float, v3[k] << 16) * w3;
            acc[2 * k + 1] += __builtin_bit_cast(float, v0[k] & 0xffff0000u) * w0
                            + __builtin_bit_cast(float, v1[k] & 0xffff0000u) * w1
                            + __builtin_bit_cast(float, v2[k] & 0xffff0000u) * w2
                            + __builtin_bit_cast(float, v3[k] & 0xffff0000u) * w3;
        }
    }
    for (; e < cend; ++e) {
        int s0 = csr[e];
        float w0 = di * nrm[e];
        u32x4 v0 = *(const u32x4*)(h + (size_t)s0 * D_OUT + lane * 8);
        #pragma unroll
        for (int k = 0; k < 4; k++) {
            acc[2 * k]     += __builtin_bit_cast(float, v0[k] << 16) * w0;
            acc[2 * k + 1] += __builtin_bit_cast(float, v0[k] & 0xffff0000u) * w0;
        }
    }
    {
        const f32x4* bp = (const f32x4*)(bias + lane * 8);
        f32x4 b0 = bp[0], b1 = bp[1];
        #pragma unroll
        for (int k = 0; k < 4; k++) { acc[k] += b0[k]; acc[4 + k] += b1[k]; }
    }
    float mx = acc[0];
    #pragma unroll
    for (int k = 1; k < 8; k++) mx = fmaxf(mx, acc[k]);
    #pragma unroll
    for (int d = 1; d < 64; d <<= 1) mx = fmaxf(mx, __shfl_xor(mx, d));
    float se = 0.f;
    #pragma unroll
    for (int k = 0; k < 8; k++) se += expf(acc[k] - mx);
    #pragma unroll
    for (int d = 1; d < 64; d <<= 1) se += __shfl_xor(se, d);
    float lse = mx + logf(se);
    f32x4 o0, o1;
    #pragma unroll
    for (int k = 0; k < 4; k++) { o0[k] = acc[k] - lse; o1[k] = acc[4 + k] - lse; }
    f32x4* op = (f32x4*)(out + (size_t)i * D_OUT + lane * 8);
    op[0] = o0; op[1] = o1;
}

// ---------------- launch ----------------
extern "C" void kernel_launch(void* const* d_in, const int* in_sizes, int n_in,
                              void* d_out, int out_size, void* d_ws, size_t ws_size,
                              hipStream_t stream) {
    const float* x    = (const float*)d_in[0];
    const int*   ei   = (const int*)d_in[1];
    const float* W    = (const float*)d_in[2];
    const float* bias = (const float*)d_in[3];
    float* out = (float*)d_out;

    const int N = in_sizes[0] / D_IN;     // 50000
    const int E = in_sizes[1] / 2;        // 400000
    const int* srcv = ei;
    const int* dstv = ei + E;

    char* p = (char*)d_ws;
    auto carve = [&](size_t b) { void* r = (void*)p; p += (b + 255) & ~(size_t)255; return r; };
    uint16_t* h    = (uint16_t*)carve((size_t)N * D_OUT * 2);            // 51.2 MB
    uint16_t* wt   = (uint16_t*)carve((size_t)D_OUT * D_IN * 2);         // 2 MB
    int*      cnt  = (int*)carve((size_t)N * 4);
    int*      cur  = (int*)carve((size_t)N * 4);
    float*    dis  = (float*)carve((size_t)N * 4);
    int*      offs = (int*)carve((size_t)N * 4);
    int*      csr  = (int*)carve((size_t)E * 4);
    float*    nrm  = (float*)carve((size_t)E * 4);
    int*      bsum = (int*)carve(1024 * 4);

    hipMemsetAsync(cnt, 0, (size_t)N * 4, stream);

    hipFuncSetAttribute((const void*)k_gemm,
                        hipFuncAttributeMaxDynamicSharedMemorySize, 131072);

    k_wt<<<dim3(D_IN / 32, D_OUT / 32), dim3(32, 8), 0, stream>>>(W, wt);
    k_count<<<(E + 255) / 256, 256, 0, stream>>>(dstv, cnt, E);
    const int nb = (N + 1023) / 1024;
    k_scan1<<<nb, 1024, 0, stream>>>(cnt, offs, bsum, dis, cur, N);
    k_scan2<<<1, 64, 0, stream>>>(bsum, nb);
    k_fill<<<(E + 255) / 256, 256, 0, stream>>>(srcv, dstv, offs, bsum, dis, cur, csr, nrm, E);

    const int nmB = (N + 127) / 128;
    k_gemm<<<nmB * 2, 512, 131072, stream>>>(x, wt, h, N);

    k_agg<<<(N + 3) / 4, 256, 0, stream>>>(h, csr, nrm, offs, bsum, cnt, dis, bias, out, N);
}

// Round 11
// 329.263 us; speedup vs baseline: 1.0621x; 1.0469x over previous
//
#include <hip/hip_runtime.h>
#include <stdint.h>

#define D_IN   2048
#define D_OUT  512

typedef __bf16 bf16;
typedef bf16     bf16x8 __attribute__((ext_vector_type(8)));
typedef float    f32x4  __attribute__((ext_vector_type(4)));
typedef uint32_t u32x4  __attribute__((ext_vector_type(4)));

#define GLP(p)  (const __attribute__((address_space(1))) void*)(p)
#define LDSP(p) (__attribute__((address_space(3))) void*)(p)

// ---------------- degree count ----------------
__global__ void k_count(const int* __restrict__ dstv, int* __restrict__ cnt, int E) {
    int e = blockIdx.x * blockDim.x + threadIdx.x;
    if (e < E) atomicAdd(&cnt[dstv[e]], 1);
}

// ---------------- hierarchical exclusive scan (+ dis, + cur=0) ----------------
__global__ __launch_bounds__(1024) void k_scan1(const int* __restrict__ cnt,
                                                int* __restrict__ offs,
                                                int* __restrict__ bsum,
                                                float* __restrict__ dis,
                                                int* __restrict__ cur, int n) {
    __shared__ int wsum[16], wbase[16];
    const int tid = threadIdx.x, lane = tid & 63, wv = tid >> 6;
    int i = blockIdx.x * 1024 + tid;
    int v = (i < n) ? cnt[i] : 0;
    int x = v;
    #pragma unroll
    for (int d = 1; d < 64; d <<= 1) {
        int y = __shfl_up(x, d);
        if (lane >= d) x += y;
    }
    if (lane == 63) wsum[wv] = x;
    __syncthreads();
    if (tid < 16) {
        int s = 0;
        for (int j = 0; j < tid; ++j) s += wsum[j];
        wbase[tid] = s;
    }
    __syncthreads();
    if (i < n) {
        offs[i] = wbase[wv] + x - v;            // block-local exclusive
        dis[i]  = rsqrtf((float)(v + 1));
        cur[i]  = 0;
    }
    if (tid == 0) bsum[blockIdx.x] = wbase[15] + wsum[15];
}

__global__ void k_scan2(int* __restrict__ bsum, int nb) {
    int t = threadIdx.x;
    if (nb <= 64) {
        int v = (t < nb) ? bsum[t] : 0;
        int x = v;
        #pragma unroll
        for (int d = 1; d < 64; d <<= 1) {
            int y = __shfl_up(x, d);
            if (t >= d) x += y;
        }
        if (t < nb) bsum[t] = x - v;   // exclusive
    } else if (t == 0) {
        int run = 0;
        for (int j = 0; j < nb; ++j) { int v = bsum[j]; bsum[j] = run; run += v; }
    }
}

// ---------------- CSR fill (offs = local + bsum); also nrm[p] = dis[src] ----------------
__global__ void k_fill(const int* __restrict__ srcv, const int* __restrict__ dstv,
                       const int* __restrict__ offs, const int* __restrict__ bsum,
                       const float* __restrict__ dis, int* __restrict__ cur,
                       int* __restrict__ csr, float* __restrict__ nrm, int E) {
    int e = blockIdx.x * blockDim.x + threadIdx.x;
    if (e < E) {
        int d = dstv[e];
        int s = srcv[e];
        int p = offs[d] + bsum[d >> 10] + atomicAdd(&cur[d], 1);
        csr[p] = s;
        nrm[p] = dis[s];
    }
}

// ---------------- weight transpose + bf16 cast: wt[n][k] = (bf16)W[k][n] ----------------
__global__ void k_wt(const float* __restrict__ W, uint16_t* __restrict__ wt) {
    __shared__ float t[32][33];
    int kb = blockIdx.x * 32, nb = blockIdx.y * 32;
    int tx = threadIdx.x, ty = threadIdx.y;
    #pragma unroll
    for (int i = 0; i < 32; i += 8)
        t[ty + i][tx] = W[(size_t)(kb + ty + i) * D_OUT + nb + tx];
    __syncthreads();
    bf16* o = (bf16*)wt;
    #pragma unroll
    for (int i = 0; i < 32; i += 8)
        o[(size_t)(nb + ty + i) * D_IN + kb + tx] = (bf16)t[tx][ty + i];
}

// ---------------- fused GEMM: H[M][512] = (bf16)X[M][2048](fp32) * W ----------------
// Empirical optimum after 9 structural variants (R2-R10): simple 2-barrier
// single-buffered loop, A staged fp32 via global_load_lds (2 x 32-col halves),
// B bf16 via global_load_lds, cvt fused into LDS read. 48 KB -> 3 blocks/CU.
// XOR involution u^(row&7) on both pre-swizzled source and LDS read.
__global__ __launch_bounds__(256) void k_gemm(const float* __restrict__ X,
                                              const uint16_t* __restrict__ WT,
                                              uint16_t* __restrict__ H, int M) {
    __shared__ float    lsA[2][128 * 32];  // 32 KB
    __shared__ uint16_t lsB[128 * 64];     // 16 KB
    // bijective chunked XCD swizzle: one m-panel's 4 n-blocks -> same XCD
    const int nwg = gridDim.x;
    const int b = blockIdx.x;
    const int q = nwg >> 3, r = nwg & 7;
    const int xcd = b & 7, lo = b >> 3;
    const int g = (xcd < r) ? (xcd * (q + 1) + lo) : (r * (q + 1) + (xcd - r) * q + lo);
    const int m0 = (g >> 2) * 128;
    const int n0 = (g & 3) * 128;
    const int tid = threadIdx.x;
    const int w = tid >> 6, lane = tid & 63;
    const int wr = w >> 1, wc = w & 1;
    const int lr = lane & 15, lk = lane >> 4;

    f32x4 acc[4][4];
    #pragma unroll
    for (int m = 0; m < 4; m++)
        #pragma unroll
        for (int n = 0; n < 4; n++) acc[m][n] = (f32x4)(0.0f);

    const float* aSrc[2][4];
    const uint16_t* bSrc[4];
    #pragma unroll
    for (int j = 0; j < 4; j++) {
        int c = w * 4 + j;
        int uidx = c * 64 + lane;
        int row = uidx >> 3, u = uidx & 7;
        int lrow = row;
        if (m0 + row >= M) lrow = (M - 1) - m0;   // clamp: valid data staged, stores masked
        const float* rbase = X + (size_t)(m0 + lrow) * D_IN;
        #pragma unroll
        for (int h = 0; h < 2; h++)
            aSrc[h][j] = rbase + h * 32 + (u ^ (row & 7)) * 4;
        bSrc[j] = WT + (size_t)(n0 + row) * D_IN + (u ^ (row & 7)) * 8;
    }

    for (int k0 = 0; k0 < D_IN; k0 += 64) {
        #pragma unroll
        for (int h = 0; h < 2; h++)
            #pragma unroll
            for (int j = 0; j < 4; j++)
                __builtin_amdgcn_global_load_lds(GLP(aSrc[h][j] + k0),
                                                 LDSP(lsA[h] + (w * 4 + j) * 256), 16, 0, 0);
        #pragma unroll
        for (int j = 0; j < 4; j++)
            __builtin_amdgcn_global_load_lds(GLP(bSrc[j] + k0),
                                             LDSP(lsB + (w * 4 + j) * 512), 16, 0, 0);
        __syncthreads();

        #pragma unroll
        for (int kk = 0; kk < 2; kk++) {
            bf16x8 aF[4], bF[4];
            #pragma unroll
            for (int m = 0; m < 4; m++) {
                int row = wr * 64 + m * 16 + lr;
                const float* base = lsA[kk] + row * 32;
                f32x4 a0 = *(const f32x4*)(base + (((2 * lk)    ) ^ (row & 7)) * 4);
                f32x4 a1 = *(const f32x4*)(base + (((2 * lk) + 1) ^ (row & 7)) * 4);
                bf16x8 af;
                af[0] = (bf16)a0[0]; af[1] = (bf16)a0[1]; af[2] = (bf16)a0[2]; af[3] = (bf16)a0[3];
                af[4] = (bf16)a1[0]; af[5] = (bf16)a1[1]; af[6] = (bf16)a1[2]; af[7] = (bf16)a1[3];
                aF[m] = af;
            }
            #pragma unroll
            for (int n = 0; n < 4; n++) {
                int row = wc * 64 + n * 16 + lr;
                bF[n] = *(const bf16x8*)((const bf16*)lsB + row * 64 + (((kk * 4 + lk) ^ (row & 7)) * 8));
            }
            #pragma unroll
            for (int m = 0; m < 4; m++)
                #pragma unroll
                for (int n = 0; n < 4; n++)
                    acc[m][n] = __builtin_amdgcn_mfma_f32_16x16x32_bf16(aF[m], bF[n], acc[m][n], 0, 0, 0);
        }
        __syncthreads();
    }

    // epilogue: C/D layout col=lane&15, row=(lane>>4)*4+reg; store bf16
    #pragma unroll
    for (int m = 0; m < 4; m++) {
        int rbase = m0 + wr * 64 + m * 16 + lk * 4;
        #pragma unroll
        for (int n = 0; n < 4; n++) {
            int col = n0 + wc * 64 + n * 16 + lr;
            #pragma unroll
            for (int j = 0; j < 4; j++) {
                int row = rbase + j;
                if (row < M) {
                    bf16 t = (bf16)acc[m][n][j];
                    H[(size_t)row * D_OUT + col] = __builtin_bit_cast(uint16_t, t);
                }
            }
        }
    }
}

// ---------------- aggregation + bias + log_softmax, one wave per node ----------------
// edge loop unrolled x2; nrm[] read linearly (no random dis gather)
__global__ __launch_bounds__(256) void k_agg(const uint16_t* __restrict__ h,
                                             const int* __restrict__ csr,
                                             const float* __restrict__ nrm,
                                             const int* __restrict__ offs,
                                             const int* __restrict__ bsum,
                                             const int* __restrict__ cnt,
                                             const float* __restrict__ dis,
                                             const float* __restrict__ bias,
                                             float* __restrict__ out, int N) {
    const int wv = threadIdx.x >> 6, lane = threadIdx.x & 63;
    const int i = blockIdx.x * 4 + wv;
    if (i >= N) return;
    const float di = dis[i];
    float acc[8];
    {
        u32x4 v = *(const u32x4*)(h + (size_t)i * D_OUT + lane * 8);
        float s2 = di * di;
        #pragma unroll
        for (int k = 0; k < 4; k++) {
            acc[2 * k]     = __builtin_bit_cast(float, v[k] << 16) * s2;
            acc[2 * k + 1] = __builtin_bit_cast(float, v[k] & 0xffff0000u) * s2;
        }
    }
    const int o = offs[i] + bsum[i >> 10], c = cnt[i];
    int e = o;
    for (; e + 2 <= o + c; e += 2) {
        int s0 = csr[e], s1 = csr[e + 1];
        float w0 = di * nrm[e], w1 = di * nrm[e + 1];
        u32x4 v0 = *(const u32x4*)(h + (size_t)s0 * D_OUT + lane * 8);
        u32x4 v1 = *(const u32x4*)(h + (size_t)s1 * D_OUT + lane * 8);
        #pragma unroll
        for (int k = 0; k < 4; k++) {
            acc[2 * k]     += __builtin_bit_cast(float, v0[k] << 16) * w0;
            acc[2 * k + 1] += __builtin_bit_cast(float, v0[k] & 0xffff0000u) * w0;
        }
        #pragma unroll
        for (int k = 0; k < 4; k++) {
            acc[2 * k]     += __builtin_bit_cast(float, v1[k] << 16) * w1;
            acc[2 * k + 1] += __builtin_bit_cast(float, v1[k] & 0xffff0000u) * w1;
        }
    }
    if (e < o + c) {
        int s0 = csr[e];
        float w0 = di * nrm[e];
        u32x4 v0 = *(const u32x4*)(h + (size_t)s0 * D_OUT + lane * 8);
        #pragma unroll
        for (int k = 0; k < 4; k++) {
            acc[2 * k]     += __builtin_bit_cast(float, v0[k] << 16) * w0;
            acc[2 * k + 1] += __builtin_bit_cast(float, v0[k] & 0xffff0000u) * w0;
        }
    }
    {
        const f32x4* bp = (const f32x4*)(bias + lane * 8);
        f32x4 b0 = bp[0], b1 = bp[1];
        #pragma unroll
        for (int k = 0; k < 4; k++) { acc[k] += b0[k]; acc[4 + k] += b1[k]; }
    }
    float mx = acc[0];
    #pragma unroll
    for (int k = 1; k < 8; k++) mx = fmaxf(mx, acc[k]);
    #pragma unroll
    for (int d = 1; d < 64; d <<= 1) mx = fmaxf(mx, __shfl_xor(mx, d));
    float se = 0.f;
    #pragma unroll
    for (int k = 0; k < 8; k++) se += expf(acc[k] - mx);
    #pragma unroll
    for (int d = 1; d < 64; d <<= 1) se += __shfl_xor(se, d);
    float lse = mx + logf(se);
    f32x4 o0, o1;
    #pragma unroll
    for (int k = 0; k < 4; k++) { o0[k] = acc[k] - lse; o1[k] = acc[4 + k] - lse; }
    f32x4* op = (f32x4*)(out + (size_t)i * D_OUT + lane * 8);
    op[0] = o0; op[1] = o1;
}

// ---------------- launch ----------------
extern "C" void kernel_launch(void* const* d_in, const int* in_sizes, int n_in,
                              void* d_out, int out_size, void* d_ws, size_t ws_size,
                              hipStream_t stream) {
    const float* x    = (const float*)d_in[0];
    const int*   ei   = (const int*)d_in[1];
    const float* W    = (const float*)d_in[2];
    const float* bias = (const float*)d_in[3];
    float* out = (float*)d_out;

    const int N = in_sizes[0] / D_IN;     // 50000
    const int E = in_sizes[1] / 2;        // 400000
    const int* srcv = ei;
    const int* dstv = ei + E;

    char* p = (char*)d_ws;
    auto carve = [&](size_t b) { void* r = (void*)p; p += (b + 255) & ~(size_t)255; return r; };
    uint16_t* h    = (uint16_t*)carve((size_t)N * D_OUT * 2);            // 51.2 MB
    uint16_t* wt   = (uint16_t*)carve((size_t)D_OUT * D_IN * 2);         // 2 MB
    int*      cnt  = (int*)carve((size_t)N * 4);
    int*      cur  = (int*)carve((size_t)N * 4);
    float*    dis  = (float*)carve((size_t)N * 4);
    int*      offs = (int*)carve((size_t)N * 4);
    int*      csr  = (int*)carve((size_t)E * 4);
    float*    nrm  = (float*)carve((size_t)E * 4);
    int*      bsum = (int*)carve(1024 * 4);

    hipMemsetAsync(cnt, 0, (size_t)N * 4, stream);

    k_wt<<<dim3(D_IN / 32, D_OUT / 32), dim3(32, 8), 0, stream>>>(W, wt);
    k_count<<<(E + 255) / 256, 256, 0, stream>>>(dstv, cnt, E);
    const int nb = (N + 1023) / 1024;
    k_scan1<<<nb, 1024, 0, stream>>>(cnt, offs, bsum, dis, cur, N);
    k_scan2<<<1, 64, 0, stream>>>(bsum, nb);
    k_fill<<<(E + 255) / 256, 256, 0, stream>>>(srcv, dstv, offs, bsum, dis, cur, csr, nrm, E);

    k_gemm<<<((N + 127) / 128) * 4, 256, 0, stream>>>(x, wt, h, N);

    k_agg<<<(N + 3) / 4, 256, 0, stream>>>(h, csr, nrm, offs, bsum, cnt, dis, bias, out, N);
}